// Round 1
// baseline (9679.163 us; speedup 1.0000x reference)
//
#include <hip/hip_runtime.h>
#include <math.h>

#define Bc 8
#define Sc 4096
#define HIDc 1280
#define CROSSc 768
#define HEADSc 20
#define HDIMc 64
#define TEXTc 77
#define ETOKc 113
#define Mc (Bc * Sc) /* 32768 */

__device__ __forceinline__ float gelu_exact(float x) {
  return 0.5f * x * (1.0f + erff(x * 0.70710678118654752440f));
}

// ---------------------------------------------------------------------------
// Generic fp32 GEMM: C = alpha * A(MxK) @ W(NxK)^T  [+ bias[n]] [+ add[m,n]]
// 64x64 tile, 256 threads, 4x4 microtile. Requires K%16==0, N%64==0.
// ---------------------------------------------------------------------------
__global__ __launch_bounds__(256) void gemm_tn(
    const float* __restrict__ A, const float* __restrict__ W,
    const float* __restrict__ bias, const float* __restrict__ add,
    float* __restrict__ C, int M, int N, int K, float alpha) {
  __shared__ float As[16][68];
  __shared__ float Ws[16][68];
  const int t = threadIdx.x;
  const int tx = t & 15, ty = t >> 4;
  const int r0 = blockIdx.y * 64, c0 = blockIdx.x * 64;
  float4 acc[4] = {};
  for (int k0 = 0; k0 < K; k0 += 16) {
#pragma unroll
    for (int i = 0; i < 4; i++) {
      int idx = t + 256 * i;
      int row = idx >> 4, kk = idx & 15;
      int gr = r0 + row, gc = c0 + row;
      As[kk][row] = (gr < M) ? A[(size_t)gr * K + k0 + kk] : 0.0f;
      Ws[kk][row] = (gc < N) ? W[(size_t)gc * K + k0 + kk] : 0.0f;
    }
    __syncthreads();
#pragma unroll
    for (int kk = 0; kk < 16; kk++) {
      const float4 av = *(const float4*)&As[kk][ty * 4];
      const float4 bv = *(const float4*)&Ws[kk][tx * 4];
      const float a_[4] = {av.x, av.y, av.z, av.w};
#pragma unroll
      for (int i = 0; i < 4; i++) {
        acc[i].x = fmaf(a_[i], bv.x, acc[i].x);
        acc[i].y = fmaf(a_[i], bv.y, acc[i].y);
        acc[i].z = fmaf(a_[i], bv.z, acc[i].z);
        acc[i].w = fmaf(a_[i], bv.w, acc[i].w);
      }
    }
    __syncthreads();
  }
#pragma unroll
  for (int i = 0; i < 4; i++) {
    int gr = r0 + ty * 4 + i;
    if (gr >= M) continue;
    const float av[4] = {acc[i].x, acc[i].y, acc[i].z, acc[i].w};
#pragma unroll
    for (int j = 0; j < 4; j++) {
      int gc = c0 + tx * 4 + j;
      float v = alpha * av[j];
      if (bias) v += bias[gc];
      if (add) v += add[(size_t)gr * N + gc];
      C[(size_t)gr * N + gc] = v;
    }
  }
}

// ---------------------------------------------------------------------------
// Fused t1 = X @ qr_w1^T + qr_b1 ; g = gelu(t1) ; logits[m,f] += g . crk[b,f,:]
// Never materializes t1/g/rq. M=32768, N=2560, K=1280. crk: (8,2,2560).
// ---------------------------------------------------------------------------
__global__ __launch_bounds__(256) void qr_logits_kernel(
    const float* __restrict__ X, const float* __restrict__ w1,
    const float* __restrict__ b1, const float* __restrict__ crk,
    float* __restrict__ logits) {
  __shared__ float As[16][68];
  __shared__ float Ws[16][68];
  const int t = threadIdx.x;
  const int tx = t & 15, ty = t >> 4;
  const int r0 = blockIdx.y * 64, c0 = blockIdx.x * 64;
  const int K = HIDc, N = 2560;
  float4 acc[4] = {};
  for (int k0 = 0; k0 < K; k0 += 16) {
#pragma unroll
    for (int i = 0; i < 4; i++) {
      int idx = t + 256 * i;
      int row = idx >> 4, kk = idx & 15;
      As[kk][row] = X[(size_t)(r0 + row) * K + k0 + kk];
      Ws[kk][row] = w1[(size_t)(c0 + row) * K + k0 + kk];
    }
    __syncthreads();
#pragma unroll
    for (int kk = 0; kk < 16; kk++) {
      const float4 av = *(const float4*)&As[kk][ty * 4];
      const float4 bv = *(const float4*)&Ws[kk][tx * 4];
      const float a_[4] = {av.x, av.y, av.z, av.w};
#pragma unroll
      for (int i = 0; i < 4; i++) {
        acc[i].x = fmaf(a_[i], bv.x, acc[i].x);
        acc[i].y = fmaf(a_[i], bv.y, acc[i].y);
        acc[i].z = fmaf(a_[i], bv.z, acc[i].z);
        acc[i].w = fmaf(a_[i], bv.w, acc[i].w);
      }
    }
    __syncthreads();
  }
  // epilogue: gelu + dot with crk for both faces, reduce across tx, atomicAdd
  const int b = r0 >> 12;  // r0 / 4096 ; 4096 % 64 == 0 so tile is one batch
  const float* crk0 = crk + (size_t)(b * 2 + 0) * 2560;
  const float* crk1 = crk + (size_t)(b * 2 + 1) * 2560;
  float p0[4] = {0.f, 0.f, 0.f, 0.f};
  float p1[4] = {0.f, 0.f, 0.f, 0.f};
#pragma unroll
  for (int i = 0; i < 4; i++) {
    const float av[4] = {acc[i].x, acc[i].y, acc[i].z, acc[i].w};
#pragma unroll
    for (int j = 0; j < 4; j++) {
      int gc = c0 + tx * 4 + j;
      float g = gelu_exact(av[j] + b1[gc]);
      p0[i] = fmaf(g, crk0[gc], p0[i]);
      p1[i] = fmaf(g, crk1[gc], p1[i]);
    }
  }
  float* red = &As[0][0];  // 1024 floats needed, 1088 available
#pragma unroll
  for (int face = 0; face < 2; face++) {
    __syncthreads();
#pragma unroll
    for (int i = 0; i < 4; i++)
      red[(ty * 4 + i) * 16 + tx] = face ? p1[i] : p0[i];
    __syncthreads();
    if (t < 64) {
      float s = 0.f;
#pragma unroll
      for (int u = 0; u < 16; u++) s += red[t * 16 + u];
      atomicAdd(&logits[(size_t)(r0 + t) * 2 + face], s);
    }
  }
}

// ---------------------------------------------------------------------------
// Small prep kernels (routing-key chain), all fp32, one thread per output.
// ---------------------------------------------------------------------------
__global__ void slice_kernel(const float* __restrict__ E, float* __restrict__ txt,
                             float* __restrict__ ip, float* __restrict__ fid) {
  int i = blockIdx.x * 256 + threadIdx.x;
  if (i >= Bc * ETOKc * CROSSc) return;
  int c = i % CROSSc;
  int rr = i / CROSSc;
  int tok = rr % ETOKc, b = rr / ETOKc;
  float v = E[i];
  if (tok < 77) txt[((size_t)b * 77 + tok) * CROSSc + c] = v;
  else if (tok < 81) ip[((size_t)b * 4 + (tok - 77)) * CROSSc + c] = v;
  else fid[((size_t)b * 32 + (tok - 81)) * CROSSc + c] = v;
}

__global__ void ragg_kernel(const float* __restrict__ E, const float* __restrict__ aw,
                            const float* __restrict__ ab, float* __restrict__ ragg) {
  int i = blockIdx.x * 256 + threadIdx.x;  // 8*2*768
  if (i >= Bc * 2 * CROSSc) return;
  int c = i % CROSSc;
  int f = (i / CROSSc) & 1;
  int b = i / (2 * CROSSc);
  const float* base = E + ((size_t)b * ETOKc + 81 + f * 16) * CROSSc + c;
  float s = ab[0];
#pragma unroll
  for (int tk = 0; tk < 16; tk++) s = fmaf(base[tk * CROSSc], aw[tk], s);
  ragg[i] = s;
}

__global__ void kr1_kernel(const float* __restrict__ ragg, const float* __restrict__ w1,
                           const float* __restrict__ b1, float* __restrict__ kr1) {
  int i = blockIdx.x * 256 + threadIdx.x;  // 16*1536
  if (i >= 16 * 1536) return;
  int j = i % 1536, bf = i / 1536;
  const float* a = ragg + (size_t)bf * CROSSc;
  const float* w = w1 + (size_t)j * CROSSc;
  float s = b1[j];
  for (int c = 0; c < CROSSc; c++) s = fmaf(a[c], w[c], s);
  kr1[i] = gelu_exact(s);
}

__global__ void rk_kernel(const float* __restrict__ kr1, const float* __restrict__ w2,
                          float* __restrict__ rk) {
  int i = blockIdx.x * 256 + threadIdx.x;  // 16*1280
  if (i >= 16 * HIDc) return;
  int d = i % HIDc, bf = i / HIDc;
  const float* a = kr1 + (size_t)bf * 1536;
  const float* w = w2 + (size_t)d * 1536;
  float s = 0.f;
  for (int j = 0; j < 1536; j++) s = fmaf(a[j], w[j], s);
  rk[i] = s;
}

__global__ void crk_kernel(const float* __restrict__ rk, const float* __restrict__ qr_w2,
                           float* __restrict__ crk) {
  int i = blockIdx.x * 256 + threadIdx.x;  // 16*2560
  if (i >= 16 * 2560) return;
  int e = i % 2560, bf = i / 2560;
  const float* r = rk + (size_t)bf * HIDc;
  float s = 0.f;
  for (int d = 0; d < HIDc; d++) s = fmaf(r[d], qr_w2[(size_t)d * 2560 + e], s);
  crk[i] = s;
}

__global__ void route_kernel(const float* __restrict__ logits, int* __restrict__ route) {
  int i = blockIdx.x * 256 + threadIdx.x;
  if (i < Mc) route[i] = (logits[2 * i + 1] > logits[2 * i]) ? 1 : 0;
}

// ---------------------------------------------------------------------------
// Fused attention: per (b, head, 256-query chunk). K/V for all three branches
// staged in LDS; per-thread online softmax; h = base + 0.6*ip + 0.7*fid[face].
// LDS rows: [0,77)=K  [77,154)=V  [154,158)=ipk  [158,162)=ipv
//           [162,194)=fk (2 faces x 16)  [194,226)=fv
// ---------------------------------------------------------------------------
__global__ __launch_bounds__(256) void attn_kernel(
    const float* __restrict__ Q, const float* __restrict__ Kb,
    const float* __restrict__ Vb, const float* __restrict__ IPK,
    const float* __restrict__ IPV, const float* __restrict__ FK,
    const float* __restrict__ FV, const int* __restrict__ route,
    float* __restrict__ H) {
  __shared__ float lds[226 * 64];
  const int t = threadIdx.x;
  const int b = blockIdx.z, hh = blockIdx.y;
  const int s0 = blockIdx.x * 256;
  for (int idx = t; idx < 226 * 16; idx += 256) {
    int row = idx >> 4, c4 = idx & 15;
    const float* src;
    if (row < 77)       src = Kb  + ((size_t)(b * 77 + row)) * HIDc;
    else if (row < 154) src = Vb  + ((size_t)(b * 77 + (row - 77))) * HIDc;
    else if (row < 158) src = IPK + ((size_t)(b * 4 + (row - 154))) * HIDc;
    else if (row < 162) src = IPV + ((size_t)(b * 4 + (row - 158))) * HIDc;
    else if (row < 194) src = FK  + ((size_t)(b * 32 + (row - 162))) * HIDc;
    else                src = FV  + ((size_t)(b * 32 + (row - 194))) * HIDc;
    ((float4*)lds)[idx] = ((const float4*)(src + hh * HDIMc))[c4];
  }
  __syncthreads();
  const size_t m = (size_t)b * Sc + s0 + t;
  const float4* qp = (const float4*)(Q + m * HIDc + hh * HDIMc);
  float4 q[16];
#pragma unroll
  for (int i = 0; i < 16; i++) q[i] = qp[i];
  float4 hacc[16] = {};
  const int face = route[m];

  auto segment = [&](int koff, int voff, int nk, float coef) {
    float mx = -1e30f, l = 0.0f;
    float4 o[16] = {};
    for (int k = 0; k < nk; k++) {
      const float4* kr = (const float4*)(lds + (koff + k) * 64);
      float d0 = 0.f, d1 = 0.f, d2 = 0.f, d3 = 0.f;
#pragma unroll
      for (int i = 0; i < 16; i++) {
        float4 kk = kr[i];
        d0 = fmaf(q[i].x, kk.x, d0);
        d1 = fmaf(q[i].y, kk.y, d1);
        d2 = fmaf(q[i].z, kk.z, d2);
        d3 = fmaf(q[i].w, kk.w, d3);
      }
      float d = ((d0 + d1) + (d2 + d3)) * 0.125f;  // SCALE = 1/sqrt(64)
      float nm = fmaxf(mx, d);
      float corr = __expf(mx - nm);
      float w = __expf(d - nm);
      l = l * corr + w;
      const float4* vr = (const float4*)(lds + (voff + k) * 64);
#pragma unroll
      for (int i = 0; i < 16; i++) {
        float4 vv = vr[i];
        o[i].x = fmaf(w, vv.x, o[i].x * corr);
        o[i].y = fmaf(w, vv.y, o[i].y * corr);
        o[i].z = fmaf(w, vv.z, o[i].z * corr);
        o[i].w = fmaf(w, vv.w, o[i].w * corr);
      }
      mx = nm;
    }
    float inv = coef / l;
#pragma unroll
    for (int i = 0; i < 16; i++) {
      hacc[i].x = fmaf(o[i].x, inv, hacc[i].x);
      hacc[i].y = fmaf(o[i].y, inv, hacc[i].y);
      hacc[i].z = fmaf(o[i].z, inv, hacc[i].z);
      hacc[i].w = fmaf(o[i].w, inv, hacc[i].w);
    }
  };
  segment(0, 77, 77, 1.0f);
  segment(154, 158, 4, 0.6f);
  segment(162 + face * 16, 194 + face * 16, 16, 0.7f);

  float4* hp = (float4*)(H + m * HIDc + hh * HDIMc);
#pragma unroll
  for (int i = 0; i < 16; i++) hp[i] = hacc[i];
}

// ---------------------------------------------------------------------------
extern "C" void kernel_launch(void* const* d_in, const int* in_sizes, int n_in,
                              void* d_out, int out_size, void* d_ws, size_t ws_size,
                              hipStream_t stream) {
  (void)in_sizes; (void)n_in; (void)out_size; (void)ws_size;
  const float* X      = (const float*)d_in[0];
  const float* E      = (const float*)d_in[1];
  const float* wq     = (const float*)d_in[2];
  const float* wk     = (const float*)d_in[3];
  const float* wv     = (const float*)d_in[4];
  const float* wo     = (const float*)d_in[5];
  const float* bo     = (const float*)d_in[6];
  const float* q_ld   = (const float*)d_in[7];
  const float* q_lu   = (const float*)d_in[8];
  const float* k_ld   = (const float*)d_in[9];
  const float* k_lu   = (const float*)d_in[10];
  const float* v_ld   = (const float*)d_in[11];
  const float* v_lu   = (const float*)d_in[12];
  const float* o_ld   = (const float*)d_in[13];
  const float* o_lu   = (const float*)d_in[14];
  const float* wk_ip  = (const float*)d_in[15];
  const float* wv_ip  = (const float*)d_in[16];
  const float* wk_fid = (const float*)d_in[17];
  const float* wv_fid = (const float*)d_in[18];
  const float* qr_w1  = (const float*)d_in[19];
  const float* qr_b1  = (const float*)d_in[20];
  const float* qr_w2  = (const float*)d_in[21];
  const float* kr_w1  = (const float*)d_in[22];
  const float* kr_b1  = (const float*)d_in[23];
  const float* kr_w2  = (const float*)d_in[24];
  const float* aggr_w = (const float*)d_in[25];
  const float* aggr_b = (const float*)d_in[26];
  float* out = (float*)d_out;

  float* ws = (float*)d_ws;
  size_t off = 0;
  auto alloc = [&](size_t n) { float* p = ws + off; off += n; return p; };
  float* Qb   = alloc((size_t)Mc * HIDc);       // query (w/ LoRA)
  float* Hb   = alloc((size_t)Mc * HIDc);       // attention output h
  float* TMP  = alloc((size_t)Mc * 128);        // xl (q-lora) then hl (o-lora)
  float* Kb   = alloc((size_t)Bc * 77 * HIDc);
  float* Vb   = alloc((size_t)Bc * 77 * HIDc);
  float* IPK  = alloc((size_t)Bc * 4 * HIDc);
  float* IPV  = alloc((size_t)Bc * 4 * HIDc);
  float* FK   = alloc((size_t)Bc * 32 * HIDc);
  float* FV   = alloc((size_t)Bc * 32 * HIDc);
  float* TXT  = alloc((size_t)Bc * 77 * CROSSc);
  float* IPC  = alloc((size_t)Bc * 4 * CROSSc);
  float* FIDC = alloc((size_t)Bc * 32 * CROSSc);
  float* TT   = alloc((size_t)Bc * 77 * 128);   // text lora tmp
  float* RAGG = alloc(16 * CROSSc);
  float* KR1  = alloc(16 * 1536);
  float* RK   = alloc(16 * HIDc);
  float* CRK  = alloc(16 * 2560);
  float* LOG  = alloc((size_t)Mc * 2);
  int*   ROUTE = (int*)alloc(Mc);

  const int Mtile = Mc / 64;  // 512

  // --- slice encoder states into contiguous text / ip / fid ---
  slice_kernel<<<(Bc * ETOKc * CROSSc + 255) / 256, 256, 0, stream>>>(E, TXT, IPC, FIDC);

  // --- routing-key chain (tiny, fp32) ---
  ragg_kernel<<<(Bc * 2 * CROSSc + 255) / 256, 256, 0, stream>>>(E, aggr_w, aggr_b, RAGG);
  kr1_kernel<<<(16 * 1536 + 255) / 256, 256, 0, stream>>>(RAGG, kr_w1, kr_b1, KR1);
  rk_kernel<<<(16 * HIDc + 255) / 256, 256, 0, stream>>>(KR1, kr_w2, RK);
  crk_kernel<<<(16 * 2560 + 255) / 256, 256, 0, stream>>>(RK, qr_w2, CRK);

  // --- fused qr MLP -> logits (fp32 for argmax fidelity) ---
  hipMemsetAsync(LOG, 0, (size_t)Mc * 2 * sizeof(float), stream);
  qr_logits_kernel<<<dim3(2560 / 64, Mtile), 256, 0, stream>>>(X, qr_w1, qr_b1, CRK, LOG);
  route_kernel<<<Mc / 256, 256, 0, stream>>>(LOG, ROUTE);

  // --- query projection + LoRA ---
  gemm_tn<<<dim3(128 / 64, Mtile), 256, 0, stream>>>(X, q_ld, nullptr, nullptr, TMP, Mc, 128, HIDc, 1.0f);
  gemm_tn<<<dim3(HIDc / 64, Mtile), 256, 0, stream>>>(X, wq, nullptr, nullptr, Qb, Mc, HIDc, HIDc, 1.0f);
  gemm_tn<<<dim3(HIDc / 64, Mtile), 256, 0, stream>>>(TMP, q_lu, nullptr, Qb, Qb, Mc, HIDc, 128, 0.6f);

  // --- text K/V + LoRA (M=616) ---
  const int Mt = Bc * 77;
  gemm_tn<<<dim3(128 / 64, (Mt + 63) / 64), 256, 0, stream>>>(TXT, k_ld, nullptr, nullptr, TT, Mt, 128, CROSSc, 1.0f);
  gemm_tn<<<dim3(HIDc / 64, (Mt + 63) / 64), 256, 0, stream>>>(TXT, wk, nullptr, nullptr, Kb, Mt, HIDc, CROSSc, 1.0f);
  gemm_tn<<<dim3(HIDc / 64, (Mt + 63) / 64), 256, 0, stream>>>(TT, k_lu, nullptr, Kb, Kb, Mt, HIDc, 128, 0.6f);
  gemm_tn<<<dim3(128 / 64, (Mt + 63) / 64), 256, 0, stream>>>(TXT, v_ld, nullptr, nullptr, TT, Mt, 128, CROSSc, 1.0f);
  gemm_tn<<<dim3(HIDc / 64, (Mt + 63) / 64), 256, 0, stream>>>(TXT, wv, nullptr, nullptr, Vb, Mt, HIDc, CROSSc, 1.0f);
  gemm_tn<<<dim3(HIDc / 64, (Mt + 63) / 64), 256, 0, stream>>>(TT, v_lu, nullptr, Vb, Vb, Mt, HIDc, 128, 0.6f);

  // --- ip K/V (M=32), fid K/V (M=256), no LoRA ---
  gemm_tn<<<dim3(HIDc / 64, 1), 256, 0, stream>>>(IPC, wk_ip, nullptr, nullptr, IPK, Bc * 4, HIDc, CROSSc, 1.0f);
  gemm_tn<<<dim3(HIDc / 64, 1), 256, 0, stream>>>(IPC, wv_ip, nullptr, nullptr, IPV, Bc * 4, HIDc, CROSSc, 1.0f);
  gemm_tn<<<dim3(HIDc / 64, 4), 256, 0, stream>>>(FIDC, wk_fid, nullptr, nullptr, FK, Bc * 32, HIDc, CROSSc, 1.0f);
  gemm_tn<<<dim3(HIDc / 64, 4), 256, 0, stream>>>(FIDC, wv_fid, nullptr, nullptr, FV, Bc * 32, HIDc, CROSSc, 1.0f);

  // --- fused triple attention ---
  attn_kernel<<<dim3(Sc / 256, HEADSc, Bc), 256, 0, stream>>>(Qb, Kb, Vb, IPK, IPV, FK, FV, ROUTE, Hb);

  // --- output projection + LoRA + bias + residual ---
  gemm_tn<<<dim3(128 / 64, Mtile), 256, 0, stream>>>(Hb, o_ld, nullptr, nullptr, TMP, Mc, 128, HIDc, 1.0f);
  gemm_tn<<<dim3(HIDc / 64, Mtile), 256, 0, stream>>>(TMP, o_lu, bo, X, out, Mc, HIDc, 128, 0.6f);
  gemm_tn<<<dim3(HIDc / 64, Mtile), 256, 0, stream>>>(Hb, wo, nullptr, out, out, Mc, HIDc, HIDc, 1.0f);
}

// Round 2
// 5009.984 us; speedup vs baseline: 1.9320x; 1.9320x over previous
//
#include <hip/hip_runtime.h>
#include <math.h>

#define Bc 8
#define Sc 4096
#define HIDc 1280
#define CROSSc 768
#define HEADSc 20
#define HDIMc 64
#define ETOKc 113
#define Mc (Bc * Sc) /* 32768 */
#define CHUNKR 4096
#define NCHUNK 8
#define QRN 2560
#define QRK 3840
#define MAXFLAG 4096

typedef unsigned short u16;
typedef __attribute__((ext_vector_type(8))) short bf16x8;
typedef __attribute__((ext_vector_type(4))) float f32x4;

__device__ __forceinline__ float b2f(u16 u) {
  union { unsigned int i; float f; } x; x.i = ((unsigned int)u) << 16; return x.f;
}
__device__ __forceinline__ u16 f2b(float f) {
  union { float f; unsigned int i; } x; x.f = f;
  unsigned int r = x.i + 0x7FFFu + ((x.i >> 16) & 1u);
  return (u16)(r >> 16);
}
__device__ __forceinline__ float gelu_exact(float x) {
  return 0.5f * x * (1.0f + erff(x * 0.70710678118654752440f));
}

// ---------------------------------------------------------------------------
// Shared GEMM building blocks: 128x128 tile, BK=64 bf16, 256 threads (4 waves
// in 2x2), each wave 4x4 grid of 16x16x32 MFMAs. A (MxK,lda) row-major, W
// (NxK,ldw) row-major (i.e. B^T). LDS tiles row-major 64 bf16/row, no padding
// (global_load_lds needs lane-contiguous LDS: base + lane*16).
// ---------------------------------------------------------------------------
__device__ __forceinline__ void stage_tiles(
    const u16* __restrict__ A, int lda, int M, int r0,
    const u16* __restrict__ W, int ldw, int N, int c0,
    int k0, u16* smA, u16* smB, int wv, int lane) {
  const int srow = lane >> 3;         // 0..7
  const int scol = (lane & 7) * 8;    // k elem offset
#pragma unroll
  for (int ci = 0; ci < 4; ci++) {
    int c = wv + ci * 4;              // chunk 0..15, wave-uniform
    int ar = r0 + c * 8 + srow; ar = ar < M ? ar : M - 1;
    const u16* ga = A + (size_t)ar * lda + k0 + scol;
    __builtin_amdgcn_global_load_lds((const __attribute__((address_space(1))) void*)ga,
                                     (__attribute__((address_space(3))) void*)(smA + c * 512), 16, 0, 0);
    int br = c0 + c * 8 + srow; br = br < N ? br : N - 1;
    const u16* gb = W + (size_t)br * ldw + k0 + scol;
    __builtin_amdgcn_global_load_lds((const __attribute__((address_space(1))) void*)gb,
                                     (__attribute__((address_space(3))) void*)(smB + c * 512), 16, 0, 0);
  }
}

__device__ __forceinline__ void mfma_tiles(const u16* smA, const u16* smB,
                                           int wr, int wc, int lane, f32x4 acc[4][4]) {
#pragma unroll
  for (int kh = 0; kh < 2; kh++) {
    const int ko = kh * 32 + (lane >> 4) * 8;  // A[m=lane&15][k=quad*8+j]
    bf16x8 af[4], bfv[4];
#pragma unroll
    for (int i = 0; i < 4; i++)
      af[i] = *(const bf16x8*)(smA + (wr * 64 + i * 16 + (lane & 15)) * 64 + ko);
#pragma unroll
    for (int j = 0; j < 4; j++)
      bfv[j] = *(const bf16x8*)(smB + (wc * 64 + j * 16 + (lane & 15)) * 64 + ko);
#pragma unroll
    for (int i = 0; i < 4; i++)
#pragma unroll
      for (int j = 0; j < 4; j++)
        acc[i][j] = __builtin_amdgcn_mfma_f32_16x16x32_bf16(af[i], bfv[j], acc[i][j], 0, 0, 0);
  }
}

// CMODE 0: fp32 out (add fp32); CMODE 1: bf16 out (add bf16).
template <int CMODE>
__global__ __launch_bounds__(256) void gemm_bf16(
    const u16* __restrict__ A, int lda, const u16* __restrict__ W, int ldw,
    int M, int N, int K, float alpha, const float* __restrict__ bias,
    const void* __restrict__ addp, void* __restrict__ Cp) {
  __shared__ __align__(16) u16 smA[128 * 64];
  __shared__ __align__(16) u16 smB[128 * 64];
  const int t = threadIdx.x, lane = t & 63, wv = t >> 6;
  const int wr = wv >> 1, wc = wv & 1;
  const int r0 = blockIdx.y * 128, c0 = blockIdx.x * 128;
  f32x4 acc[4][4] = {};
  for (int k0 = 0; k0 < K; k0 += 64) {
    stage_tiles(A, lda, M, r0, W, ldw, N, c0, k0, smA, smB, wv, lane);
    __syncthreads();
    mfma_tiles(smA, smB, wr, wc, lane, acc);
    __syncthreads();
  }
  const int cl = lane & 15, quad = lane >> 4;
#pragma unroll
  for (int i = 0; i < 4; i++) {
#pragma unroll
    for (int j = 0; j < 4; j++) {
      int gc = c0 + wc * 64 + j * 16 + cl;
      if (gc >= N) continue;
      float bv = bias ? bias[gc] : 0.0f;
#pragma unroll
      for (int r = 0; r < 4; r++) {
        int gr = r0 + wr * 64 + i * 16 + quad * 4 + r;  // D: col=lane&15, row=quad*4+reg
        if (gr >= M) continue;
        float v = alpha * acc[i][j][r] + bv;
        if (CMODE == 0) {
          const float* add = (const float*)addp;
          if (add) v += add[(size_t)gr * N + gc];
          ((float*)Cp)[(size_t)gr * N + gc] = v;
        } else {
          const u16* add = (const u16*)addp;
          if (add) v += b2f(add[(size_t)gr * N + gc]);
          ((u16*)Cp)[(size_t)gr * N + gc] = f2b(v);
        }
      }
    }
  }
}

// Split-bf16 qr GEMM (K=3840 = hi.hi + hi.lo + lo.hi) with fused
// gelu(t1+b1) . crk epilogue -> atomic partial logits. M=CHUNKR, N=QRN.
__global__ __launch_bounds__(256) void gemm_qr(
    const u16* __restrict__ A, const u16* __restrict__ W,
    const float* __restrict__ b1, const float* __restrict__ crk0,
    const float* __restrict__ crk1, float* __restrict__ LOG, int mbase) {
  __shared__ __align__(16) u16 smA[128 * 64];
  __shared__ __align__(16) u16 smB[128 * 64];
  const int t = threadIdx.x, lane = t & 63, wv = t >> 6;
  const int wr = wv >> 1, wc = wv & 1;
  const int r0 = blockIdx.y * 128, c0 = blockIdx.x * 128;
  f32x4 acc[4][4] = {};
  for (int k0 = 0; k0 < QRK; k0 += 64) {
    stage_tiles(A, QRK, CHUNKR, r0, W, QRK, QRN, c0, k0, smA, smB, wv, lane);
    __syncthreads();
    mfma_tiles(smA, smB, wr, wc, lane, acc);
    __syncthreads();
  }
  const int cl = lane & 15, quad = lane >> 4;
#pragma unroll
  for (int i = 0; i < 4; i++) {
    float p0[4] = {0.f, 0.f, 0.f, 0.f};
    float p1[4] = {0.f, 0.f, 0.f, 0.f};
#pragma unroll
    for (int j = 0; j < 4; j++) {
      int gc = c0 + wc * 64 + j * 16 + cl;
      float bv = b1[gc], c0v = crk0[gc], c1v = crk1[gc];
#pragma unroll
      for (int r = 0; r < 4; r++) {
        float g = gelu_exact(acc[i][j][r] + bv);
        p0[r] = fmaf(g, c0v, p0[r]);
        p1[r] = fmaf(g, c1v, p1[r]);
      }
    }
#pragma unroll
    for (int off = 1; off < 16; off <<= 1) {
#pragma unroll
      for (int r = 0; r < 4; r++) {
        p0[r] += __shfl_xor(p0[r], off);
        p1[r] += __shfl_xor(p1[r], off);
      }
    }
    if (cl == 0) {
#pragma unroll
      for (int r = 0; r < 4; r++) {
        int gm = mbase + r0 + wr * 64 + i * 16 + quad * 4 + r;
        atomicAdd(&LOG[2 * gm + 0], p0[r]);
        atomicAdd(&LOG[2 * gm + 1], p1[r]);
      }
    }
  }
}

// ---------------------------------------------------------------------------
// Casts
// ---------------------------------------------------------------------------
__global__ void cast_bf16_kernel(const float* __restrict__ src, u16* __restrict__ dst, int n4) {
  int i = blockIdx.x * 256 + threadIdx.x;
  if (i >= n4) return;
  float4 v = ((const float4*)src)[i];
  ushort4 o;
  o.x = f2b(v.x); o.y = f2b(v.y); o.z = f2b(v.z); o.w = f2b(v.w);
  ((ushort4*)dst)[i] = o;
}

__global__ void castX_chunk_kernel(const float* __restrict__ X, u16* __restrict__ Xb,
                                   u16* __restrict__ Xcat, int rowstart) {
  int i = blockIdx.x * 256 + threadIdx.x;
  if (i >= CHUNKR * HIDc) return;
  int r = i / HIDc, c = i % HIDc;
  float x = X[(size_t)(rowstart + r) * HIDc + c];
  u16 hi = f2b(x);
  u16 lob = f2b(x - b2f(hi));
  Xb[(size_t)(rowstart + r) * HIDc + c] = hi;
  size_t rb = (size_t)r * QRK;
  Xcat[rb + c] = hi; Xcat[rb + HIDc + c] = hi; Xcat[rb + 2 * HIDc + c] = lob;
}

__global__ void cast_w1_kernel(const float* __restrict__ w1, u16* __restrict__ W1cat) {
  int i = blockIdx.x * 256 + threadIdx.x;
  if (i >= QRN * HIDc) return;
  int r = i / HIDc, c = i % HIDc;
  float w = w1[i];
  u16 hi = f2b(w);
  u16 lob = f2b(w - b2f(hi));
  size_t rb = (size_t)r * QRK;
  W1cat[rb + c] = hi; W1cat[rb + HIDc + c] = lob; W1cat[rb + 2 * HIDc + c] = hi;
}

__global__ void slice_kernel(const float* __restrict__ E, u16* __restrict__ txt,
                             u16* __restrict__ ip, u16* __restrict__ fid) {
  int i = blockIdx.x * 256 + threadIdx.x;
  if (i >= Bc * ETOKc * CROSSc) return;
  int c = i % CROSSc;
  int rr = i / CROSSc;
  int tok = rr % ETOKc, b = rr / ETOKc;
  u16 v = f2b(E[i]);
  if (tok < 77) txt[((size_t)b * 77 + tok) * CROSSc + c] = v;
  else if (tok < 81) ip[((size_t)b * 4 + (tok - 77)) * CROSSc + c] = v;
  else fid[((size_t)b * 32 + (tok - 81)) * CROSSc + c] = v;
}

// ---------------------------------------------------------------------------
// Routing-key chain (tiny, fp32, unchanged from round 1) + tau
// ---------------------------------------------------------------------------
__global__ void ragg_kernel(const float* __restrict__ E, const float* __restrict__ aw,
                            const float* __restrict__ ab, float* __restrict__ ragg) {
  int i = blockIdx.x * 256 + threadIdx.x;
  if (i >= Bc * 2 * CROSSc) return;
  int c = i % CROSSc;
  int f = (i / CROSSc) & 1;
  int b = i / (2 * CROSSc);
  const float* base = E + ((size_t)b * ETOKc + 81 + f * 16) * CROSSc + c;
  float s = ab[0];
#pragma unroll
  for (int tk = 0; tk < 16; tk++) s = fmaf(base[tk * CROSSc], aw[tk], s);
  ragg[i] = s;
}

__global__ void kr1_kernel(const float* __restrict__ ragg, const float* __restrict__ w1,
                           const float* __restrict__ b1, float* __restrict__ kr1) {
  int i = blockIdx.x * 256 + threadIdx.x;
  if (i >= 16 * 1536) return;
  int j = i % 1536, bf = i / 1536;
  const float* a = ragg + (size_t)bf * CROSSc;
  const float* w = w1 + (size_t)j * CROSSc;
  float s = b1[j];
  for (int c = 0; c < CROSSc; c++) s = fmaf(a[c], w[c], s);
  kr1[i] = gelu_exact(s);
}

__global__ void rk_kernel(const float* __restrict__ kr1, const float* __restrict__ w2,
                          float* __restrict__ rk) {
  int i = blockIdx.x * 256 + threadIdx.x;
  if (i >= 16 * HIDc) return;
  int d = i % HIDc, bf = i / HIDc;
  const float* a = kr1 + (size_t)bf * 1536;
  const float* w = w2 + (size_t)d * 1536;
  float s = 0.f;
  for (int j = 0; j < 1536; j++) s = fmaf(a[j], w[j], s);
  rk[i] = s;
}

__global__ void crk_kernel(const float* __restrict__ rk, const float* __restrict__ qr_w2,
                           float* __restrict__ crk) {
  int i = blockIdx.x * 256 + threadIdx.x;
  if (i >= 16 * QRN) return;
  int e = i % QRN, bf = i / QRN;
  const float* r = rk + (size_t)bf * HIDc;
  float s = 0.f;
  for (int d = 0; d < HIDc; d++) s = fmaf(r[d], qr_w2[(size_t)d * QRN + e], s);
  crk[i] = s;
}

__global__ void tau_kernel(const float* __restrict__ crk, float* __restrict__ tau) {
  __shared__ float red[256];
  int t = threadIdx.x, b = blockIdx.x;
  const float* c0 = crk + (size_t)(b * 2) * QRN;
  const float* c1 = c0 + QRN;
  float s = 0.f;
  for (int e = t; e < QRN; e += 256) { float d = c0[e] - c1[e]; s = fmaf(d, d, s); }
  red[t] = s; __syncthreads();
  for (int o = 128; o; o >>= 1) { if (t < o) red[t] += red[t + o]; __syncthreads(); }
  if (t == 0) tau[b] = 1e-4f * sqrtf(red[0]);  // ~22x split-bf16 err rms
}

__global__ void route_flag_kernel(const float* __restrict__ LOG, const float* __restrict__ tau,
                                  int* __restrict__ route, int* __restrict__ flags,
                                  int* __restrict__ count) {
  int i = blockIdx.x * 256 + threadIdx.x;
  if (i >= Mc) return;
  float l0 = LOG[2 * i], l1 = LOG[2 * i + 1];
  route[i] = (l1 > l0) ? 1 : 0;
  if (fabsf(l1 - l0) < tau[i >> 12]) {
    int idx = atomicAdd(count, 1);
    if (idx < MAXFLAG) flags[idx] = i;
  }
}

// Exact fp32 recompute of routing for near-tie rows.
__global__ __launch_bounds__(256) void fixup_kernel(
    const float* __restrict__ X, const float* __restrict__ w1,
    const float* __restrict__ b1, const float* __restrict__ crk,
    const int* __restrict__ flags, const int* __restrict__ count,
    int* __restrict__ route) {
  __shared__ float xr[HIDc];
  __shared__ float r0s[4], r1s[4];
  int n = *count; if (n > MAXFLAG) n = MAXFLAG;
  for (int fi = blockIdx.x; fi < n; fi += gridDim.x) {
    int m = flags[fi];
    int b = m >> 12;
    __syncthreads();
    for (int k = threadIdx.x; k < HIDc; k += 256) xr[k] = X[(size_t)m * HIDc + k];
    __syncthreads();
    float p0 = 0.f, p1 = 0.f;
    for (int e = threadIdx.x; e < QRN; e += 256) {
      const float* w = w1 + (size_t)e * HIDc;
      float s = b1[e];
      for (int k = 0; k < HIDc; k++) s = fmaf(xr[k], w[k], s);
      float g = gelu_exact(s);
      p0 = fmaf(g, crk[(size_t)(b * 2) * QRN + e], p0);
      p1 = fmaf(g, crk[(size_t)(b * 2 + 1) * QRN + e], p1);
    }
    for (int o = 32; o; o >>= 1) { p0 += __shfl_down(p0, o); p1 += __shfl_down(p1, o); }
    int wvi = threadIdx.x >> 6;
    if ((threadIdx.x & 63) == 0) { r0s[wvi] = p0; r1s[wvi] = p1; }
    __syncthreads();
    if (threadIdx.x == 0)
      route[m] = ((r1s[0] + r1s[1] + r1s[2] + r1s[3]) >
                  (r0s[0] + r0s[1] + r0s[2] + r0s[3])) ? 1 : 0;
    __syncthreads();
  }
}

// ---------------------------------------------------------------------------
// Fused triple attention (bf16 Q in, bf16 H out; K/V fp32 in LDS as before)
// ---------------------------------------------------------------------------
__global__ __launch_bounds__(256) void attn_kernel(
    const u16* __restrict__ Q, const float* __restrict__ Kb,
    const float* __restrict__ Vb, const float* __restrict__ IPK,
    const float* __restrict__ IPV, const float* __restrict__ FK,
    const float* __restrict__ FV, const int* __restrict__ route,
    u16* __restrict__ H) {
  __shared__ float lds[226 * 64];
  const int t = threadIdx.x;
  const int b = blockIdx.z, hh = blockIdx.y;
  const int s0 = blockIdx.x * 256;
  for (int idx = t; idx < 226 * 16; idx += 256) {
    int row = idx >> 4, c4 = idx & 15;
    const float* src;
    if (row < 77)       src = Kb  + ((size_t)(b * 77 + row)) * HIDc;
    else if (row < 154) src = Vb  + ((size_t)(b * 77 + (row - 77))) * HIDc;
    else if (row < 158) src = IPK + ((size_t)(b * 4 + (row - 154))) * HIDc;
    else if (row < 162) src = IPV + ((size_t)(b * 4 + (row - 158))) * HIDc;
    else if (row < 194) src = FK  + ((size_t)(b * 32 + (row - 162))) * HIDc;
    else                src = FV  + ((size_t)(b * 32 + (row - 194))) * HIDc;
    ((float4*)lds)[idx] = ((const float4*)(src + hh * HDIMc))[c4];
  }
  __syncthreads();
  const size_t m = (size_t)b * Sc + s0 + t;
  const u16* qp = Q + m * HIDc + hh * HDIMc;
  float4 q[16];
#pragma unroll
  for (int i = 0; i < 16; i++) {
    ushort4 u = ((const ushort4*)qp)[i];
    q[i] = make_float4(b2f(u.x), b2f(u.y), b2f(u.z), b2f(u.w));
  }
  float4 hacc[16] = {};
  const int face = route[m];

  auto segment = [&](int koff, int voff, int nk, float coef) {
    float mx = -1e30f, l = 0.0f;
    float4 o[16] = {};
    for (int k = 0; k < nk; k++) {
      const float4* kr = (const float4*)(lds + (koff + k) * 64);
      float d0 = 0.f, d1 = 0.f, d2 = 0.f, d3 = 0.f;
#pragma unroll
      for (int i = 0; i < 16; i++) {
        float4 kk = kr[i];
        d0 = fmaf(q[i].x, kk.x, d0);
        d1 = fmaf(q[i].y, kk.y, d1);
        d2 = fmaf(q[i].z, kk.z, d2);
        d3 = fmaf(q[i].w, kk.w, d3);
      }
      float d = ((d0 + d1) + (d2 + d3)) * 0.125f;
      float nm = fmaxf(mx, d);
      float corr = __expf(mx - nm);
      float w = __expf(d - nm);
      l = l * corr + w;
      const float4* vr = (const float4*)(lds + (voff + k) * 64);
#pragma unroll
      for (int i = 0; i < 16; i++) {
        float4 vv = vr[i];
        o[i].x = fmaf(w, vv.x, o[i].x * corr);
        o[i].y = fmaf(w, vv.y, o[i].y * corr);
        o[i].z = fmaf(w, vv.z, o[i].z * corr);
        o[i].w = fmaf(w, vv.w, o[i].w * corr);
      }
      mx = nm;
    }
    float inv = coef / l;
#pragma unroll
    for (int i = 0; i < 16; i++) {
      hacc[i].x = fmaf(o[i].x, inv, hacc[i].x);
      hacc[i].y = fmaf(o[i].y, inv, hacc[i].y);
      hacc[i].z = fmaf(o[i].z, inv, hacc[i].z);
      hacc[i].w = fmaf(o[i].w, inv, hacc[i].w);
    }
  };
  segment(0, 77, 77, 1.0f);
  segment(154, 158, 4, 0.6f);
  segment(162 + face * 16, 194 + face * 16, 16, 0.7f);

  u16* hp = H + m * HIDc + hh * HDIMc;
#pragma unroll
  for (int i = 0; i < 16; i++) {
    ushort4 u;
    u.x = f2b(hacc[i].x); u.y = f2b(hacc[i].y); u.z = f2b(hacc[i].z); u.w = f2b(hacc[i].w);
    ((ushort4*)hp)[i] = u;
  }
}

// ---------------------------------------------------------------------------
extern "C" void kernel_launch(void* const* d_in, const int* in_sizes, int n_in,
                              void* d_out, int out_size, void* d_ws, size_t ws_size,
                              hipStream_t stream) {
  (void)in_sizes; (void)n_in; (void)out_size; (void)ws_size;
  const float* X      = (const float*)d_in[0];
  const float* E      = (const float*)d_in[1];
  const float* wq     = (const float*)d_in[2];
  const float* wk     = (const float*)d_in[3];
  const float* wv     = (const float*)d_in[4];
  const float* wo     = (const float*)d_in[5];
  const float* bo     = (const float*)d_in[6];
  const float* q_ld   = (const float*)d_in[7];
  const float* q_lu   = (const float*)d_in[8];
  const float* k_ld   = (const float*)d_in[9];
  const float* k_lu   = (const float*)d_in[10];
  const float* v_ld   = (const float*)d_in[11];
  const float* v_lu   = (const float*)d_in[12];
  const float* o_ld   = (const float*)d_in[13];
  const float* o_lu   = (const float*)d_in[14];
  const float* wk_ip  = (const float*)d_in[15];
  const float* wv_ip  = (const float*)d_in[16];
  const float* wk_fid = (const float*)d_in[17];
  const float* wv_fid = (const float*)d_in[18];
  const float* qr_w1  = (const float*)d_in[19];
  const float* qr_b1  = (const float*)d_in[20];
  const float* qr_w2  = (const float*)d_in[21];
  const float* kr_w1  = (const float*)d_in[22];
  const float* kr_b1  = (const float*)d_in[23];
  const float* kr_w2  = (const float*)d_in[24];
  const float* aggr_w = (const float*)d_in[25];
  const float* aggr_b = (const float*)d_in[26];
  float* out = (float*)d_out;

  char* base = (char*)d_ws;
  size_t off = 0;
  auto alloc = [&](size_t bytes) -> void* {
    off = (off + 255) & ~(size_t)255;
    void* p = base + off; off += bytes; return p;
  };
  // ws total ~352 MB (<= 363 MB proven in round 1)
  u16* Xb    = (u16*)alloc((size_t)Mc * HIDc * 2);
  u16* Xcat  = (u16*)alloc((size_t)CHUNKR * QRK * 2);
  u16* W1cat = (u16*)alloc((size_t)QRN * QRK * 2);
  u16* Qb    = (u16*)alloc((size_t)Mc * HIDc * 2);
  u16* Hb    = (u16*)alloc((size_t)Mc * HIDc * 2);
  u16* TMPb  = (u16*)alloc((size_t)Mc * 128 * 2);
  u16* TMPo  = (u16*)alloc((size_t)Mc * 128 * 2);
  float* Kb  = (float*)alloc((size_t)Bc * 77 * HIDc * 4);
  float* Vb  = (float*)alloc((size_t)Bc * 77 * HIDc * 4);
  float* IPK = (float*)alloc((size_t)Bc * 4 * HIDc * 4);
  float* IPV = (float*)alloc((size_t)Bc * 4 * HIDc * 4);
  float* FK  = (float*)alloc((size_t)Bc * 32 * HIDc * 4);
  float* FV  = (float*)alloc((size_t)Bc * 32 * HIDc * 4);
  u16* TXTb  = (u16*)alloc((size_t)Bc * 77 * CROSSc * 2);
  u16* IPCb  = (u16*)alloc((size_t)Bc * 4 * CROSSc * 2);
  u16* FIDCb = (u16*)alloc((size_t)Bc * 32 * CROSSc * 2);
  u16* TTb   = (u16*)alloc((size_t)Bc * 77 * 128 * 2);
  u16* wqb   = (u16*)alloc((size_t)HIDc * HIDc * 2);
  u16* wob   = (u16*)alloc((size_t)HIDc * HIDc * 2);
  u16* wkb   = (u16*)alloc((size_t)HIDc * CROSSc * 2);
  u16* wvb   = (u16*)alloc((size_t)HIDc * CROSSc * 2);
  u16* wkipb = (u16*)alloc((size_t)HIDc * CROSSc * 2);
  u16* wvipb = (u16*)alloc((size_t)HIDc * CROSSc * 2);
  u16* wkfb  = (u16*)alloc((size_t)HIDc * CROSSc * 2);
  u16* wvfb  = (u16*)alloc((size_t)HIDc * CROSSc * 2);
  u16* qldb  = (u16*)alloc((size_t)128 * HIDc * 2);
  u16* qlub  = (u16*)alloc((size_t)HIDc * 128 * 2);
  u16* kldb  = (u16*)alloc((size_t)128 * CROSSc * 2);
  u16* klub  = (u16*)alloc((size_t)HIDc * 128 * 2);
  u16* vldb  = (u16*)alloc((size_t)128 * CROSSc * 2);
  u16* vlub  = (u16*)alloc((size_t)HIDc * 128 * 2);
  u16* oldb  = (u16*)alloc((size_t)128 * HIDc * 2);
  u16* olub  = (u16*)alloc((size_t)HIDc * 128 * 2);
  float* RAGG = (float*)alloc(16 * CROSSc * 4);
  float* KR1  = (float*)alloc(16 * 1536 * 4);
  float* RK   = (float*)alloc(16 * HIDc * 4);
  float* CRK  = (float*)alloc(16 * QRN * 4);
  float* TAU  = (float*)alloc(Bc * 4);
  float* LOG  = (float*)alloc((size_t)Mc * 2 * 4);
  int* ROUTE  = (int*)alloc((size_t)Mc * 4);
  int* FLAGS  = (int*)alloc(MAXFLAG * 4);
  int* COUNT  = (int*)alloc(4);

  auto castW = [&](const float* s, u16* d, int n) {
    cast_bf16_kernel<<<(n / 4 + 255) / 256, 256, 0, stream>>>(s, d, n / 4);
  };
  auto G0 = [&](const u16* A, int lda, const u16* W, int ldw, int M, int N, int K,
                float alpha, const float* bias, const float* add, float* C) {
    gemm_bf16<0><<<dim3(N / 128, (M + 127) / 128), 256, 0, stream>>>(
        A, lda, W, ldw, M, N, K, alpha, bias, (const void*)add, (void*)C);
  };
  auto G1 = [&](const u16* A, int lda, const u16* W, int ldw, int M, int N, int K,
                float alpha, const u16* add, u16* C) {
    gemm_bf16<1><<<dim3(N / 128, (M + 127) / 128), 256, 0, stream>>>(
        A, lda, W, ldw, M, N, K, alpha, nullptr, (const void*)add, (void*)C);
  };

  // --- slices + routing-key chain + tau ---
  slice_kernel<<<(Bc * ETOKc * CROSSc + 255) / 256, 256, 0, stream>>>(E, TXTb, IPCb, FIDCb);
  ragg_kernel<<<(Bc * 2 * CROSSc + 255) / 256, 256, 0, stream>>>(E, aggr_w, aggr_b, RAGG);
  kr1_kernel<<<(16 * 1536 + 255) / 256, 256, 0, stream>>>(RAGG, kr_w1, kr_b1, KR1);
  rk_kernel<<<(16 * HIDc + 255) / 256, 256, 0, stream>>>(KR1, kr_w2, RK);
  crk_kernel<<<(16 * QRN + 255) / 256, 256, 0, stream>>>(RK, qr_w2, CRK);
  tau_kernel<<<Bc, 256, 0, stream>>>(CRK, TAU);

  // --- weight casts ---
  castW(wq, wqb, HIDc * HIDc);     castW(wo, wob, HIDc * HIDc);
  castW(wk, wkb, HIDc * CROSSc);   castW(wv, wvb, HIDc * CROSSc);
  castW(wk_ip, wkipb, HIDc * CROSSc); castW(wv_ip, wvipb, HIDc * CROSSc);
  castW(wk_fid, wkfb, HIDc * CROSSc); castW(wv_fid, wvfb, HIDc * CROSSc);
  castW(q_ld, qldb, 128 * HIDc);   castW(q_lu, qlub, HIDc * 128);
  castW(k_ld, kldb, 128 * CROSSc); castW(k_lu, klub, HIDc * 128);
  castW(v_ld, vldb, 128 * CROSSc); castW(v_lu, vlub, HIDc * 128);
  castW(o_ld, oldb, 128 * HIDc);   castW(o_lu, olub, HIDc * 128);
  cast_w1_kernel<<<(QRN * HIDc + 255) / 256, 256, 0, stream>>>(qr_w1, W1cat);

  // --- split-bf16 qr MLP -> logits (chunked over M; chunk == batch) ---
  hipMemsetAsync(LOG, 0, (size_t)Mc * 2 * 4, stream);
  hipMemsetAsync(COUNT, 0, 4, stream);
  for (int ch = 0; ch < NCHUNK; ch++) {
    castX_chunk_kernel<<<(CHUNKR * HIDc + 255) / 256, 256, 0, stream>>>(X, Xb, Xcat, ch * CHUNKR);
    gemm_qr<<<dim3(QRN / 128, CHUNKR / 128), 256, 0, stream>>>(
        Xcat, W1cat, qr_b1, CRK + (size_t)(ch * 2) * QRN, CRK + (size_t)(ch * 2 + 1) * QRN,
        LOG, ch * CHUNKR);
  }
  route_flag_kernel<<<(Mc + 255) / 256, 256, 0, stream>>>(LOG, TAU, ROUTE, FLAGS, COUNT);
  fixup_kernel<<<64, 256, 0, stream>>>(X, qr_w1, qr_b1, CRK, FLAGS, COUNT, ROUTE);

  // --- query projection + LoRA (bf16 MFMA) ---
  G1(Xb, HIDc, qldb, HIDc, Mc, 128, HIDc, 1.0f, nullptr, TMPb);
  G1(Xb, HIDc, wqb, HIDc, Mc, HIDc, HIDc, 1.0f, nullptr, Qb);
  G1(TMPb, 128, qlub, 128, Mc, HIDc, 128, 0.6f, Qb, Qb);

  // --- text K/V + LoRA ---
  const int Mt = Bc * 77;
  G0(TXTb, CROSSc, wkb, CROSSc, Mt, HIDc, CROSSc, 1.0f, nullptr, nullptr, Kb);
  G1(TXTb, CROSSc, kldb, CROSSc, Mt, 128, CROSSc, 1.0f, nullptr, TTb);
  G0(TTb, 128, klub, 128, Mt, HIDc, 128, 0.6f, nullptr, Kb, Kb);
  G0(TXTb, CROSSc, wvb, CROSSc, Mt, HIDc, CROSSc, 1.0f, nullptr, nullptr, Vb);
  G1(TXTb, CROSSc, vldb, CROSSc, Mt, 128, CROSSc, 1.0f, nullptr, TTb);
  G0(TTb, 128, vlub, 128, Mt, HIDc, 128, 0.6f, nullptr, Vb, Vb);

  // --- ip / fid K,V ---
  G0(IPCb, CROSSc, wkipb, CROSSc, Bc * 4, HIDc, CROSSc, 1.0f, nullptr, nullptr, IPK);
  G0(IPCb, CROSSc, wvipb, CROSSc, Bc * 4, HIDc, CROSSc, 1.0f, nullptr, nullptr, IPV);
  G0(FIDCb, CROSSc, wkfb, CROSSc, Bc * 32, HIDc, CROSSc, 1.0f, nullptr, nullptr, FK);
  G0(FIDCb, CROSSc, wvfb, CROSSc, Bc * 32, HIDc, CROSSc, 1.0f, nullptr, nullptr, FV);

  // --- fused triple attention ---
  attn_kernel<<<dim3(Sc / 256, HEADSc, Bc), 256, 0, stream>>>(Qb, Kb, Vb, IPK, IPV, FK, FV, ROUTE, Hb);

  // --- output projection + LoRA + bias + residual ---
  G1(Hb, HIDc, oldb, HIDc, Mc, 128, HIDc, 1.0f, nullptr, TMPo);
  G0(TMPo, 128, olub, 128, Mc, HIDc, 128, 0.6f, bo, X, out);
  G0(Hb, HIDc, wob, HIDc, Mc, HIDc, HIDc, 1.0f, nullptr, out, out);
}